// Round 11
// baseline (167.902 us; speedup 1.0000x reference)
//
#include <hip/hip_runtime.h>
#include <hip/hip_bf16.h>

// SupConLoss fused: logits = text @ image^T (bf16 MFMA), masked two-sided
// logsumexp with fixed shift, softplus-mean -> scalar.
// B = N = 8192, D = 256, NUM_CLASSES = 64, T = 1.
//
// R11: DIAGNOSTIC ROUND. Main kernel = R9 unchanged (~55us). Added two
// amplified probe dispatches (no output writes, values kept live via asm
// sinks) to decompose the 55us wall that four structural variants all hit:
//   probe_noepi (2x tiles): staging+ds_read+MFMA, no epilogue.
//   probe_stage (6x tiles): staging+barriers only.
// Per-dispatch rocprof rows give the marginal cost of each phase.

#define B_ROWS   8192
#define N_COLS   8192
#define DIM      256
#define CSPLIT   32                        // grid = (64, 32) = 2048 blocks
#define NTILES   ((N_COLS / CSPLIT) / 32)  // 8 col-tiles of 32 per block
#define BLK_ROWS 128                       // 4 waves x 32 rows
#define THREADS  256

typedef __attribute__((ext_vector_type(8))) short bf16x8;  // 8 bf16 = 4 VGPR
typedef __attribute__((ext_vector_type(4))) float f32x4;   // 16x16 MFMA acc

#if __has_builtin(__builtin_amdgcn_exp2f)
#define EXP2F(x) __builtin_amdgcn_exp2f(x)
#else
#define EXP2F(x) exp2f(x)
#endif
#if __has_builtin(__builtin_amdgcn_logf)
#define LOG2F(x) __builtin_amdgcn_logf(x)
#else
#define LOG2F(x) log2f(x)
#endif

__device__ __forceinline__ unsigned short f2bf(float f) {
    union { float f; unsigned u; } c; c.f = f;
    return (unsigned short)((c.u + 0x7FFFu + ((c.u >> 16) & 1u)) >> 16);
}

// Stage one 16 KB tile (4 x global_load_lds width-16 per thread).
__device__ __forceinline__ void stage_tile(const char* bsrc, char* ldsd,
                                           int T, int BUF) {
#pragma unroll
    for (int i_ = 0; i_ < 4; ++i_)
        __builtin_amdgcn_global_load_lds(
            (const __attribute__((address_space(1))) unsigned int*)
                (bsrc + (size_t)T * 16384 + i_ * 4096),
            (__attribute__((address_space(3))) unsigned int*)
                (ldsd + (size_t)BUF * 16384 + i_ * 4096),
            16, 0, 0);
}

// One dispatch: zero gsum, cvt A (row-major bf16), cvt+transpose B into Bt
// (the LDS/fragment chunk image: group g, chunk c holds
//  B[g*32+(c&31)][k=(c>>5)*8..+8)).
__global__ void cvt_all_kernel(const float* __restrict__ text,
                               const float* __restrict__ img,
                               unsigned short* __restrict__ Abf,
                               unsigned short* __restrict__ Bt,
                               float* __restrict__ gsum) {
    const int i = blockIdx.x * blockDim.x + threadIdx.x;   // [0, 524288)
    if (i < 4096) {
        reinterpret_cast<float4*>(gsum)[i] = float4{0.f, 0.f, 0.f, 0.f};
    }
    if (i < 262144) {
        const float4* src = reinterpret_cast<const float4*>(text) + i * 2;
        float4 v0 = src[0], v1 = src[1];
        unsigned short s[8];
        s[0] = f2bf(v0.x); s[1] = f2bf(v0.y); s[2] = f2bf(v0.z); s[3] = f2bf(v0.w);
        s[4] = f2bf(v1.x); s[5] = f2bf(v1.y); s[6] = f2bf(v1.z); s[7] = f2bf(v1.w);
        reinterpret_cast<bf16x8*>(Abf)[i] = *reinterpret_cast<const bf16x8*>(s);
    } else {
        const int C = i - 262144;           // Bt chunk id, [0, 262144)
        const int g = C >> 10, c = C & 1023;
        const int col = g * 32 + (c & 31);
        const int k8  = c >> 5;
        const float4* src =
            reinterpret_cast<const float4*>(img + (size_t)col * DIM + k8 * 8);
        float4 v0 = src[0], v1 = src[1];
        unsigned short s[8];
        s[0] = f2bf(v0.x); s[1] = f2bf(v0.y); s[2] = f2bf(v0.z); s[3] = f2bf(v0.w);
        s[4] = f2bf(v1.x); s[5] = f2bf(v1.y); s[6] = f2bf(v1.z); s[7] = f2bf(v1.w);
        reinterpret_cast<bf16x8*>(Bt)[C] = *reinterpret_cast<const bf16x8*>(s);
    }
}

// ---------------- main kernel: identical to R9 ----------------
__launch_bounds__(THREADS, 3)
__global__ void fused_gemm_lse(const unsigned short* __restrict__ Abf,
                               const unsigned short* __restrict__ Bt,
                               const int* __restrict__ tlab,
                               const int* __restrict__ itgt,
                               float* __restrict__ gsum_p,
                               float* __restrict__ gsum_n) {
    __shared__ char lds[2 * 16384] __attribute__((aligned(128)));

    const int tid  = threadIdx.x;
    const int lane = tid & 63;
    const int wave = tid >> 6;
    const int l15  = lane & 15;
    const int q    = lane >> 4;
    const int rb   = blockIdx.x * BLK_ROWS + wave * 32;
    const int cb0  = blockIdx.y * (N_COLS / CSPLIT);

    bf16x8 afrag0[8], afrag1[8];
    const bf16x8* arow0 =
        reinterpret_cast<const bf16x8*>(Abf + (size_t)(rb + l15) * DIM) + q;
    const bf16x8* arow1 =
        reinterpret_cast<const bf16x8*>(Abf + (size_t)(rb + 16 + l15) * DIM) + q;
#pragma unroll
    for (int ks = 0; ks < 8; ++ks) {
        afrag0[ks] = arow0[ks * 4];
        afrag1[ks] = arow1[ks * 4];
    }

    int rowcls0[4], rowcls1[4];
#pragma unroll
    for (int j = 0; j < 4; ++j) {
        rowcls0[j] = tlab[rb + q * 4 + j];
        rowcls1[j] = tlab[rb + 16 + q * 4 + j];
    }

    float sump0[4] = {0, 0, 0, 0}, sumn0[4] = {0, 0, 0, 0};
    float sump1[4] = {0, 0, 0, 0}, sumn1[4] = {0, 0, 0, 0};

    const char* bsrc = (const char*)Bt
        + ((size_t)blockIdx.y * NTILES) * 16384 + tid * 16;
    char* ldsd = lds + tid * 16;

    const float L2E = 1.4426950408889634f;
    const float C2  = 72.0f;

    stage_tile(bsrc, ldsd, 0, 0);

    for (int t = 0; t < NTILES; ++t) {
        __syncthreads();
        if (t + 1 < NTILES) stage_tile(bsrc, ldsd, t + 1, (t + 1) & 1);

        const int cc0 = itgt[cb0 + t * 32 + l15];
        const int cc1 = itgt[cb0 + t * 32 + 16 + l15];

        f32x4 acc00 = {0, 0, 0, 0}, acc01 = {0, 0, 0, 0};
        f32x4 acc10 = {0, 0, 0, 0}, acc11 = {0, 0, 0, 0};
        const char* bb = lds + (t & 1) * 16384 + q * 512 + l15 * 16;
#pragma unroll
        for (int ks = 0; ks < 8; ++ks) {
            bf16x8 b0 = *reinterpret_cast<const bf16x8*>(bb + ks * 2048);
            bf16x8 b1 = *reinterpret_cast<const bf16x8*>(bb + ks * 2048 + 256);
            acc00 = __builtin_amdgcn_mfma_f32_16x16x32_bf16(afrag0[ks], b0,
                                                            acc00, 0, 0, 0);
            acc01 = __builtin_amdgcn_mfma_f32_16x16x32_bf16(afrag0[ks], b1,
                                                            acc01, 0, 0, 0);
            acc10 = __builtin_amdgcn_mfma_f32_16x16x32_bf16(afrag1[ks], b0,
                                                            acc10, 0, 0, 0);
            acc11 = __builtin_amdgcn_mfma_f32_16x16x32_bf16(afrag1[ks], b1,
                                                            acc11, 0, 0, 0);
        }

#pragma unroll
        for (int j = 0; j < 4; ++j) {
            {
                const float x = acc00[j];
                const bool  p = (rowcls0[j] == cc0);
                const float e = EXP2F(__builtin_fmaf(x, p ? -L2E : L2E, -C2));
                sump0[j] += p ? e : 0.f;
                sumn0[j] += p ? 0.f : e;
            }
            {
                const float x = acc01[j];
                const bool  p = (rowcls0[j] == cc1);
                const float e = EXP2F(__builtin_fmaf(x, p ? -L2E : L2E, -C2));
                sump0[j] += p ? e : 0.f;
                sumn0[j] += p ? 0.f : e;
            }
            {
                const float x = acc10[j];
                const bool  p = (rowcls1[j] == cc0);
                const float e = EXP2F(__builtin_fmaf(x, p ? -L2E : L2E, -C2));
                sump1[j] += p ? e : 0.f;
                sumn1[j] += p ? 0.f : e;
            }
            {
                const float x = acc11[j];
                const bool  p = (rowcls1[j] == cc1);
                const float e = EXP2F(__builtin_fmaf(x, p ? -L2E : L2E, -C2));
                sump1[j] += p ? e : 0.f;
                sumn1[j] += p ? 0.f : e;
            }
        }
    }

#pragma unroll
    for (int j = 0; j < 4; ++j) {
        float vp0 = sump0[j], vn0 = sumn0[j];
        float vp1 = sump1[j], vn1 = sumn1[j];
#pragma unroll
        for (int m = 1; m < 16; m <<= 1) {
            vp0 += __shfl_xor(vp0, m, 64);
            vn0 += __shfl_xor(vn0, m, 64);
            vp1 += __shfl_xor(vp1, m, 64);
            vn1 += __shfl_xor(vn1, m, 64);
        }
        if (l15 == 0) {
            const int row0 = rb + q * 4 + j;
            atomicAdd(&gsum_p[row0], vp0);
            atomicAdd(&gsum_n[row0], vn0);
            const int row1 = rb + 16 + q * 4 + j;
            atomicAdd(&gsum_p[row1], vp1);
            atomicAdd(&gsum_n[row1], vn1);
        }
    }
}

// ---------------- probe P1: no epilogue, 2x tiles ----------------
__launch_bounds__(THREADS, 3)
__global__ void gemm_probe_noepi(const unsigned short* __restrict__ Abf,
                                 const unsigned short* __restrict__ Bt) {
    __shared__ char lds[2 * 16384] __attribute__((aligned(128)));

    const int tid  = threadIdx.x;
    const int lane = tid & 63;
    const int wave = tid >> 6;
    const int l15  = lane & 15;
    const int q    = lane >> 4;
    const int rb   = blockIdx.x * BLK_ROWS + wave * 32;

    bf16x8 afrag0[8], afrag1[8];
    const bf16x8* arow0 =
        reinterpret_cast<const bf16x8*>(Abf + (size_t)(rb + l15) * DIM) + q;
    const bf16x8* arow1 =
        reinterpret_cast<const bf16x8*>(Abf + (size_t)(rb + 16 + l15) * DIM) + q;
#pragma unroll
    for (int ks = 0; ks < 8; ++ks) {
        afrag0[ks] = arow0[ks * 4];
        afrag1[ks] = arow1[ks * 4];
    }

    const char* bsrc = (const char*)Bt
        + ((size_t)blockIdx.y * NTILES) * 16384 + tid * 16;
    char* ldsd = lds + tid * 16;

    stage_tile(bsrc, ldsd, 0, 0);

    const int ITERS = 2 * NTILES;   // 2x amplification
#pragma unroll 1
    for (int it = 0; it < ITERS; ++it) {
        __syncthreads();
        if (it + 1 < ITERS)
            stage_tile(bsrc, ldsd, (it + 1) & (NTILES - 1), (it + 1) & 1);

        f32x4 acc00 = {0, 0, 0, 0}, acc01 = {0, 0, 0, 0};
        f32x4 acc10 = {0, 0, 0, 0}, acc11 = {0, 0, 0, 0};
        const char* bb = lds + (it & 1) * 16384 + q * 512 + l15 * 16;
#pragma unroll
        for (int ks = 0; ks < 8; ++ks) {
            bf16x8 b0 = *reinterpret_cast<const bf16x8*>(bb + ks * 2048);
            bf16x8 b1 = *reinterpret_cast<const bf16x8*>(bb + ks * 2048 + 256);
            acc00 = __builtin_amdgcn_mfma_f32_16x16x32_bf16(afrag0[ks], b0,
                                                            acc00, 0, 0, 0);
            acc01 = __builtin_amdgcn_mfma_f32_16x16x32_bf16(afrag0[ks], b1,
                                                            acc01, 0, 0, 0);
            acc10 = __builtin_amdgcn_mfma_f32_16x16x32_bf16(afrag1[ks], b0,
                                                            acc10, 0, 0, 0);
            acc11 = __builtin_amdgcn_mfma_f32_16x16x32_bf16(afrag1[ks], b1,
                                                            acc11, 0, 0, 0);
        }
        // Keep the MFMA results live without computing the epilogue.
#pragma unroll
        for (int j = 0; j < 4; ++j) {
            asm volatile("" :: "v"(acc00[j]), "v"(acc01[j]),
                              "v"(acc10[j]), "v"(acc11[j]));
        }
    }
}

// ---------------- probe P2: staging + barriers only, 6x tiles ----------------
__launch_bounds__(THREADS, 3)
__global__ void gemm_probe_stage(const unsigned short* __restrict__ Bt) {
    __shared__ char lds[2 * 16384] __attribute__((aligned(128)));

    const int tid = threadIdx.x;
    const char* bsrc = (const char*)Bt
        + ((size_t)blockIdx.y * NTILES) * 16384 + tid * 16;
    char* ldsd = lds + tid * 16;

    stage_tile(bsrc, ldsd, 0, 0);

    const int ITERS = 6 * NTILES;   // 6x amplification
#pragma unroll 1
    for (int it = 0; it < ITERS; ++it) {
        __syncthreads();
        if (it + 1 < ITERS)
            stage_tile(bsrc, ldsd, (it + 1) & (NTILES - 1), (it + 1) & 1);
    }
}

// lse_{p,n} = (log2(S) + C2) * ln2 ; loss = mean softplus(lse_p + lse_n)
__global__ void finalize_kernel(const float* __restrict__ gsum_p,
                                const float* __restrict__ gsum_n,
                                float* __restrict__ out) {
    __shared__ float red[1024];
    const float LN2 = 0.6931471805599453f;
    const float C2  = 72.0f;
    float acc = 0.f;
    for (int i = threadIdx.x; i < B_ROWS; i += 1024) {
        float zp = (LOG2F(gsum_p[i]) + C2) * LN2;
        float zn = (LOG2F(gsum_n[i]) + C2) * LN2;
        float z  = zp + zn;
        float sp = fmaxf(z, 0.f) + log1pf(expf(-fabsf(z)));
        acc += sp;
    }
    red[threadIdx.x] = acc;
    __syncthreads();
    for (int s = 512; s > 0; s >>= 1) {
        if ((int)threadIdx.x < s) red[threadIdx.x] += red[threadIdx.x + s];
        __syncthreads();
    }
    if (threadIdx.x == 0) out[0] = red[0] / (float)B_ROWS;
}

extern "C" void kernel_launch(void* const* d_in, const int* in_sizes, int n_in,
                              void* d_out, int out_size, void* d_ws, size_t ws_size,
                              hipStream_t stream) {
    const float* text = (const float*)d_in[0];   // [B, D] f32
    const float* img  = (const float*)d_in[1];   // [N, D] f32
    const int* tlab   = (const int*)d_in[2];     // [B]
    const int* itgt   = (const int*)d_in[3];     // [N]
    float* out        = (float*)d_out;           // scalar f32

    char* ws = (char*)d_ws;
    unsigned short* Abf = (unsigned short*)(ws);                            // 4 MB
    unsigned short* Bt  = (unsigned short*)(ws + (size_t)B_ROWS * DIM * 2); // 4 MB
    float* gsum_p = (float*)(ws + (size_t)(B_ROWS + N_COLS) * DIM * 2);
    float* gsum_n = gsum_p + B_ROWS;

    cvt_all_kernel<<<(2 * 262144) / 256, 256, 0, stream>>>(text, img, Abf, Bt,
                                                           gsum_p);

    dim3 grid(B_ROWS / BLK_ROWS, CSPLIT);
    fused_gemm_lse<<<grid, THREADS, 0, stream>>>(Abf, Bt, tlab, itgt,
                                                 gsum_p, gsum_n);

    finalize_kernel<<<1, 1024, 0, stream>>>(gsum_p, gsum_n, out);

    // Diagnostic probes (no output writes; amplified so they surface in the
    // duration-sorted top-5 rocprof table).
    gemm_probe_noepi<<<grid, THREADS, 0, stream>>>(Abf, Bt);
    gemm_probe_stage<<<grid, THREADS, 0, stream>>>(Bt);
}

// Round 12
// 74.112 us; speedup vs baseline: 2.2655x; 2.2655x over previous
//
#include <hip/hip_runtime.h>
#include <hip/hip_bf16.h>

// SupConLoss fused: logits = text @ image^T (bf16 MFMA), masked two-sided
// logsumexp with fixed shift, softplus-mean -> scalar.
// B = N = 8192, D = 256, NUM_CLASSES = 64, T = 1.
//
// R12: cross-tile software pipeline. R11 probes decomposed the 55us wall:
// stage skeleton 9.5us, +ds_read/MFMA = 28.5us (MfmaUtil 53%), +epilogue
// = 55us (MfmaUtil 25%) -- the epilogue's VALU work serializes against the
// matrix pipe within each wave. Here tile t's MFMAs (acc set B) issue while
// tile t-1's epilogue (acc set A) runs on the VALU pipe: two named acc sets,
// 2x-unrolled loop (static indexing, rule #20). Epilogue trimmed with the
// R10-verified sumn-unconditional trick (subtract sump after reduce).

#define B_ROWS   8192
#define N_COLS   8192
#define DIM      256
#define CSPLIT   32                        // grid = (64, 32) = 2048 blocks
#define NTILES   ((N_COLS / CSPLIT) / 32)  // 8 col-tiles of 32 per block
#define BLK_ROWS 128                       // 4 waves x 32 rows
#define THREADS  256

typedef __attribute__((ext_vector_type(8))) short bf16x8;  // 8 bf16 = 4 VGPR
typedef __attribute__((ext_vector_type(4))) float f32x4;   // 16x16 MFMA acc

#if __has_builtin(__builtin_amdgcn_exp2f)
#define EXP2F(x) __builtin_amdgcn_exp2f(x)
#else
#define EXP2F(x) exp2f(x)
#endif
#if __has_builtin(__builtin_amdgcn_logf)
#define LOG2F(x) __builtin_amdgcn_logf(x)
#else
#define LOG2F(x) log2f(x)
#endif

__device__ __forceinline__ unsigned short f2bf(float f) {
    union { float f; unsigned u; } c; c.f = f;
    return (unsigned short)((c.u + 0x7FFFu + ((c.u >> 16) & 1u)) >> 16);
}

// Stage one 16 KB tile (4 x global_load_lds width-16 per thread).
__device__ __forceinline__ void stage_tile(const char* bsrc, char* ldsd,
                                           int T, int BUF) {
#pragma unroll
    for (int i_ = 0; i_ < 4; ++i_)
        __builtin_amdgcn_global_load_lds(
            (const __attribute__((address_space(1))) unsigned int*)
                (bsrc + (size_t)T * 16384 + i_ * 4096),
            (__attribute__((address_space(3))) unsigned int*)
                (ldsd + (size_t)BUF * 16384 + i_ * 4096),
            16, 0, 0);
}

// e = exp2(+/-x*log2e - C2); sumn accumulates e unconditionally (positive
// contributions subtracted after the reduce -- R10-verified, absmax 0.0).
__device__ __forceinline__ void epi_one(float x, bool p, float& sn, float& sp) {
    const float L2E = 1.4426950408889634f;
    const float C2  = 72.0f;
    const float e = EXP2F(__builtin_fmaf(x, p ? -L2E : L2E, -C2));
    sn += e;
    sp += p ? e : 0.f;
}

// One dispatch: zero gsum, cvt A (row-major bf16), cvt+transpose B into Bt
// (the LDS/fragment chunk image: group g, chunk c holds
//  B[g*32+(c&31)][k=(c>>5)*8..+8)).
__global__ void cvt_all_kernel(const float* __restrict__ text,
                               const float* __restrict__ img,
                               unsigned short* __restrict__ Abf,
                               unsigned short* __restrict__ Bt,
                               float* __restrict__ gsum) {
    const int i = blockIdx.x * blockDim.x + threadIdx.x;   // [0, 524288)
    if (i < 4096) {
        reinterpret_cast<float4*>(gsum)[i] = float4{0.f, 0.f, 0.f, 0.f};
    }
    if (i < 262144) {
        const float4* src = reinterpret_cast<const float4*>(text) + i * 2;
        float4 v0 = src[0], v1 = src[1];
        unsigned short s[8];
        s[0] = f2bf(v0.x); s[1] = f2bf(v0.y); s[2] = f2bf(v0.z); s[3] = f2bf(v0.w);
        s[4] = f2bf(v1.x); s[5] = f2bf(v1.y); s[6] = f2bf(v1.z); s[7] = f2bf(v1.w);
        reinterpret_cast<bf16x8*>(Abf)[i] = *reinterpret_cast<const bf16x8*>(s);
    } else {
        const int C = i - 262144;           // Bt chunk id, [0, 262144)
        const int g = C >> 10, c = C & 1023;
        const int col = g * 32 + (c & 31);
        const int k8  = c >> 5;
        const float4* src =
            reinterpret_cast<const float4*>(img + (size_t)col * DIM + k8 * 8);
        float4 v0 = src[0], v1 = src[1];
        unsigned short s[8];
        s[0] = f2bf(v0.x); s[1] = f2bf(v0.y); s[2] = f2bf(v0.z); s[3] = f2bf(v0.w);
        s[4] = f2bf(v1.x); s[5] = f2bf(v1.y); s[6] = f2bf(v1.z); s[7] = f2bf(v1.w);
        reinterpret_cast<bf16x8*>(Bt)[C] = *reinterpret_cast<const bf16x8*>(s);
    }
}

// mfma_f32_16x16x32_bf16 layouts (R5-verified, absmax 0.0):
//   A: row = lane&15, k = 8*(lane>>4)+j
//   B: col = lane&15, k = 8*(lane>>4)+j
//   C: col = lane&15, row = (lane>>4)*4 + j
// LDS tile (16 KB): chunk c=(k8*32+col) at byte c*16.
__launch_bounds__(THREADS, 2)
__global__ void fused_gemm_lse(const unsigned short* __restrict__ Abf,
                               const unsigned short* __restrict__ Bt,
                               const int* __restrict__ tlab,
                               const int* __restrict__ itgt,
                               float* __restrict__ gsum_p,
                               float* __restrict__ gsum_n) {
    __shared__ char lds[2 * 16384] __attribute__((aligned(128)));

    const int tid  = threadIdx.x;
    const int lane = tid & 63;
    const int wave = tid >> 6;
    const int l15  = lane & 15;
    const int q    = lane >> 4;
    const int rb   = blockIdx.x * BLK_ROWS + wave * 32;
    const int cb0  = blockIdx.y * (N_COLS / CSPLIT);

    bf16x8 afrag0[8], afrag1[8];
    const bf16x8* arow0 =
        reinterpret_cast<const bf16x8*>(Abf + (size_t)(rb + l15) * DIM) + q;
    const bf16x8* arow1 =
        reinterpret_cast<const bf16x8*>(Abf + (size_t)(rb + 16 + l15) * DIM) + q;
#pragma unroll
    for (int ks = 0; ks < 8; ++ks) {
        afrag0[ks] = arow0[ks * 4];
        afrag1[ks] = arow1[ks * 4];
    }

    int rowcls0[4], rowcls1[4];
#pragma unroll
    for (int j = 0; j < 4; ++j) {
        rowcls0[j] = tlab[rb + q * 4 + j];
        rowcls1[j] = tlab[rb + 16 + q * 4 + j];
    }

    float sump0[4] = {0, 0, 0, 0}, sumn0[4] = {0, 0, 0, 0};
    float sump1[4] = {0, 0, 0, 0}, sumn1[4] = {0, 0, 0, 0};

    const char* bsrc = (const char*)Bt
        + ((size_t)blockIdx.y * NTILES) * 16384 + tid * 16;
    char* ldsd = lds + tid * 16;

// COMPUTE: 16 ds_read_b128 + 32 MFMA for one tile into the named acc set.
#define COMPUTE(A00, A01, A10, A11, BUF) do {                                 \
    const char* bb_ = lds + (BUF) * 16384 + q * 512 + l15 * 16;               \
    _Pragma("unroll")                                                         \
    for (int ks = 0; ks < 8; ++ks) {                                          \
        bf16x8 b0_ = *reinterpret_cast<const bf16x8*>(bb_ + ks * 2048);       \
        bf16x8 b1_ = *reinterpret_cast<const bf16x8*>(bb_ + ks * 2048 + 256); \
        A00 = __builtin_amdgcn_mfma_f32_16x16x32_bf16(afrag0[ks], b0_, A00,   \
                                                      0, 0, 0);               \
        A01 = __builtin_amdgcn_mfma_f32_16x16x32_bf16(afrag0[ks], b1_, A01,   \
                                                      0, 0, 0);               \
        A10 = __builtin_amdgcn_mfma_f32_16x16x32_bf16(afrag1[ks], b0_, A10,   \
                                                      0, 0, 0);               \
        A11 = __builtin_amdgcn_mfma_f32_16x16x32_bf16(afrag1[ks], b1_, A11,   \
                                                      0, 0, 0);               \
    }                                                                         \
} while (0)

// EPI: register-only epilogue for one tile's acc set (overlaps the other
// set's in-flight MFMAs on the matrix pipe).
#define EPI(A00, A01, A10, A11, CC0, CC1) do {                                \
    _Pragma("unroll")                                                         \
    for (int j = 0; j < 4; ++j) {                                             \
        epi_one(A00[j], rowcls0[j] == (CC0), sumn0[j], sump0[j]);             \
        epi_one(A01[j], rowcls0[j] == (CC1), sumn0[j], sump0[j]);             \
        epi_one(A10[j], rowcls1[j] == (CC0), sumn1[j], sump1[j]);             \
        epi_one(A11[j], rowcls1[j] == (CC1), sumn1[j], sump1[j]);             \
    }                                                                         \
} while (0)

    f32x4 a00, a01, a10, a11;   // pipeline set A (odd tiles)
    f32x4 b00, b01, b10, b11;   // pipeline set B (even tiles)
    int ccA0 = 0, ccA1 = 0, ccB0, ccB1;
    const f32x4 z4 = {0.f, 0.f, 0.f, 0.f};

    stage_tile(bsrc, ldsd, 0, 0);

#pragma unroll
    for (int t = 0; t < NTILES; t += 2) {
        __syncthreads();                       // tile t staged (buf0)
        if (t + 1 < NTILES) stage_tile(bsrc, ldsd, t + 1, 1);
        ccB0 = itgt[cb0 + t * 32 + l15];
        ccB1 = itgt[cb0 + t * 32 + 16 + l15];
        b00 = z4; b01 = z4; b10 = z4; b11 = z4;
        COMPUTE(b00, b01, b10, b11, 0);        // MFMAs of tile t ...
        if (t > 0) EPI(a00, a01, a10, a11, ccA0, ccA1);  // ... overlap EPI(t-1)

        __syncthreads();                       // tile t+1 staged (buf1)
        if (t + 2 < NTILES) stage_tile(bsrc, ldsd, t + 2, 0);
        ccA0 = itgt[cb0 + (t + 1) * 32 + l15];
        ccA1 = itgt[cb0 + (t + 1) * 32 + 16 + l15];
        a00 = z4; a01 = z4; a10 = z4; a11 = z4;
        COMPUTE(a00, a01, a10, a11, 1);        // MFMAs of tile t+1 ...
        EPI(b00, b01, b10, b11, ccB0, ccB1);   // ... overlap EPI(t)
    }
    EPI(a00, a01, a10, a11, ccA0, ccA1);       // last tile's epilogue

#undef COMPUTE
#undef EPI

    // Reduce over the 16 cols of each quarter-wave, then one atomic per row.
    // gsum_n receives (sumn_raw - sump) = true negative-side sum.
#pragma unroll
    for (int j = 0; j < 4; ++j) {
        float vp0 = sump0[j], vn0 = sumn0[j];
        float vp1 = sump1[j], vn1 = sumn1[j];
#pragma unroll
        for (int m = 1; m < 16; m <<= 1) {
            vp0 += __shfl_xor(vp0, m, 64);
            vn0 += __shfl_xor(vn0, m, 64);
            vp1 += __shfl_xor(vp1, m, 64);
            vn1 += __shfl_xor(vn1, m, 64);
        }
        if (l15 == 0) {
            const int row0 = rb + q * 4 + j;
            atomicAdd(&gsum_p[row0], vp0);
            atomicAdd(&gsum_n[row0], vn0 - vp0);
            const int row1 = rb + 16 + q * 4 + j;
            atomicAdd(&gsum_p[row1], vp1);
            atomicAdd(&gsum_n[row1], vn1 - vp1);
        }
    }
}

// lse_{p,n} = (log2(S) + C2) * ln2 ; loss = mean softplus(lse_p + lse_n)
__global__ void finalize_kernel(const float* __restrict__ gsum_p,
                                const float* __restrict__ gsum_n,
                                float* __restrict__ out) {
    __shared__ float red[1024];
    const float LN2 = 0.6931471805599453f;
    const float C2  = 72.0f;
    float acc = 0.f;
    for (int i = threadIdx.x; i < B_ROWS; i += 1024) {
        float zp = (LOG2F(gsum_p[i]) + C2) * LN2;
        float zn = (LOG2F(gsum_n[i]) + C2) * LN2;
        float z  = zp + zn;
        float sp = fmaxf(z, 0.f) + log1pf(expf(-fabsf(z)));
        acc += sp;
    }
    red[threadIdx.x] = acc;
    __syncthreads();
    for (int s = 512; s > 0; s >>= 1) {
        if ((int)threadIdx.x < s) red[threadIdx.x] += red[threadIdx.x + s];
        __syncthreads();
    }
    if (threadIdx.x == 0) out[0] = red[0] / (float)B_ROWS;
}

extern "C" void kernel_launch(void* const* d_in, const int* in_sizes, int n_in,
                              void* d_out, int out_size, void* d_ws, size_t ws_size,
                              hipStream_t stream) {
    const float* text = (const float*)d_in[0];   // [B, D] f32
    const float* img  = (const float*)d_in[1];   // [N, D] f32
    const int* tlab   = (const int*)d_in[2];     // [B]
    const int* itgt   = (const int*)d_in[3];     // [N]
    float* out        = (float*)d_out;           // scalar f32

    char* ws = (char*)d_ws;
    unsigned short* Abf = (unsigned short*)(ws);                            // 4 MB
    unsigned short* Bt  = (unsigned short*)(ws + (size_t)B_ROWS * DIM * 2); // 4 MB
    float* gsum_p = (float*)(ws + (size_t)(B_ROWS + N_COLS) * DIM * 2);
    float* gsum_n = gsum_p + B_ROWS;

    cvt_all_kernel<<<(2 * 262144) / 256, 256, 0, stream>>>(text, img, Abf, Bt,
                                                           gsum_p);

    dim3 grid(B_ROWS / BLK_ROWS, CSPLIT);
    fused_gemm_lse<<<grid, THREADS, 0, stream>>>(Abf, Bt, tlab, itgt,
                                                 gsum_p, gsum_n);

    finalize_kernel<<<1, 1024, 0, stream>>>(gsum_p, gsum_n, out);
}

// Round 13
// 70.883 us; speedup vs baseline: 2.3687x; 1.0456x over previous
//
#include <hip/hip_runtime.h>
#include <hip/hip_bf16.h>

// SupConLoss fused: logits = text @ image^T (bf16 MFMA), masked two-sided
// logsumexp with fixed shift, softplus-mean -> scalar.
// B = N = 8192, D = 256, NUM_CLASSES = 64, T = 1.
//
// R13 = R9 structure + slim epilogue. R11 probes + R9 counters showed the
// epilogue costs 16us of VALU pipe (8 instr/elem) + ~10us serialization.
// Slimming: (1) log2(e) folded into A at conversion (MFMA outputs y=x*log2e,
// fma->add); (2) uniform path = {add, exp2, add} per element into sumn;
// (3) positives (1/64 of elements) handled in a divergent branch computing
// the complement exp2(-y-72) exactly. R12's 2-deep acc pipeline reverted
// (occupancy collapse, T15 non-transfer confirmed).

#define B_ROWS   8192
#define N_COLS   8192
#define DIM      256
#define CSPLIT   32                        // grid = (64, 32) = 2048 blocks
#define NTILES   ((N_COLS / CSPLIT) / 32)  // 8 col-tiles of 32 per block
#define BLK_ROWS 128                       // 4 waves x 32 rows
#define THREADS  256

typedef __attribute__((ext_vector_type(8))) short bf16x8;  // 8 bf16 = 4 VGPR
typedef __attribute__((ext_vector_type(4))) float f32x4;   // 16x16 MFMA acc

#if __has_builtin(__builtin_amdgcn_exp2f)
#define EXP2F(x) __builtin_amdgcn_exp2f(x)
#else
#define EXP2F(x) exp2f(x)
#endif
#if __has_builtin(__builtin_amdgcn_logf)
#define LOG2F(x) __builtin_amdgcn_logf(x)
#else
#define LOG2F(x) log2f(x)
#endif

__device__ __forceinline__ unsigned short f2bf(float f) {
    union { float f; unsigned u; } c; c.f = f;
    return (unsigned short)((c.u + 0x7FFFu + ((c.u >> 16) & 1u)) >> 16);
}

// Stage one 16 KB tile (4 x global_load_lds width-16 per thread).
__device__ __forceinline__ void stage_tile(const char* bsrc, char* ldsd,
                                           int T, int BUF) {
#pragma unroll
    for (int i_ = 0; i_ < 4; ++i_)
        __builtin_amdgcn_global_load_lds(
            (const __attribute__((address_space(1))) unsigned int*)
                (bsrc + (size_t)T * 16384 + i_ * 4096),
            (__attribute__((address_space(3))) unsigned int*)
                (ldsd + (size_t)BUF * 16384 + i_ * 4096),
            16, 0, 0);
}

// Slim epilogue, y = x*log2(e) from the scaled-A MFMA:
//   uniform: u = 2^(y-72), sumn += u                      (add, exp2, add)
//   positive (1/64): v = 2^(-y-72) = e^-x * 2^-72 exactly; route u out of
//   sumn and v into sump inside a divergent branch (SALU overhead only).
__device__ __forceinline__ void epi_one(float y, bool p, float& sn, float& sp) {
    const float u = EXP2F(y - 72.0f);
    sn += u;
    if (p) {
        const float v = EXP2F(-y - 72.0f);
        sp += v;
        sn -= u;
    }
}

// One dispatch: zero gsum, cvt A (row-major bf16, PRE-SCALED by log2e),
// cvt+transpose B into Bt (the LDS/fragment chunk image: group g, chunk c
// holds B[g*32+(c&31)][k=(c>>5)*8..+8)).
__global__ void cvt_all_kernel(const float* __restrict__ text,
                               const float* __restrict__ img,
                               unsigned short* __restrict__ Abf,
                               unsigned short* __restrict__ Bt,
                               float* __restrict__ gsum) {
    const float L2E = 1.4426950408889634f;
    const int i = blockIdx.x * blockDim.x + threadIdx.x;   // [0, 524288)
    if (i < 4096) {
        reinterpret_cast<float4*>(gsum)[i] = float4{0.f, 0.f, 0.f, 0.f};
    }
    if (i < 262144) {
        const float4* src = reinterpret_cast<const float4*>(text) + i * 2;
        float4 v0 = src[0], v1 = src[1];
        unsigned short s[8];
        s[0] = f2bf(v0.x * L2E); s[1] = f2bf(v0.y * L2E);
        s[2] = f2bf(v0.z * L2E); s[3] = f2bf(v0.w * L2E);
        s[4] = f2bf(v1.x * L2E); s[5] = f2bf(v1.y * L2E);
        s[6] = f2bf(v1.z * L2E); s[7] = f2bf(v1.w * L2E);
        reinterpret_cast<bf16x8*>(Abf)[i] = *reinterpret_cast<const bf16x8*>(s);
    } else {
        const int C = i - 262144;           // Bt chunk id, [0, 262144)
        const int g = C >> 10, c = C & 1023;
        const int col = g * 32 + (c & 31);
        const int k8  = c >> 5;
        const float4* src =
            reinterpret_cast<const float4*>(img + (size_t)col * DIM + k8 * 8);
        float4 v0 = src[0], v1 = src[1];
        unsigned short s[8];
        s[0] = f2bf(v0.x); s[1] = f2bf(v0.y); s[2] = f2bf(v0.z); s[3] = f2bf(v0.w);
        s[4] = f2bf(v1.x); s[5] = f2bf(v1.y); s[6] = f2bf(v1.z); s[7] = f2bf(v1.w);
        reinterpret_cast<bf16x8*>(Bt)[C] = *reinterpret_cast<const bf16x8*>(s);
    }
}

// mfma_f32_16x16x32_bf16 layouts (R5-verified, absmax 0.0):
//   A: row = lane&15, k = 8*(lane>>4)+j
//   B: col = lane&15, k = 8*(lane>>4)+j
//   C: col = lane&15, row = (lane>>4)*4 + j
// LDS tile (16 KB): chunk c=(k8*32+col) at byte c*16.
__launch_bounds__(THREADS, 3)
__global__ void fused_gemm_lse(const unsigned short* __restrict__ Abf,
                               const unsigned short* __restrict__ Bt,
                               const int* __restrict__ tlab,
                               const int* __restrict__ itgt,
                               float* __restrict__ gsum_p,
                               float* __restrict__ gsum_n) {
    __shared__ char lds[2 * 16384] __attribute__((aligned(128)));

    const int tid  = threadIdx.x;
    const int lane = tid & 63;
    const int wave = tid >> 6;
    const int l15  = lane & 15;
    const int q    = lane >> 4;
    const int rb   = blockIdx.x * BLK_ROWS + wave * 32;
    const int cb0  = blockIdx.y * (N_COLS / CSPLIT);

    bf16x8 afrag0[8], afrag1[8];
    const bf16x8* arow0 =
        reinterpret_cast<const bf16x8*>(Abf + (size_t)(rb + l15) * DIM) + q;
    const bf16x8* arow1 =
        reinterpret_cast<const bf16x8*>(Abf + (size_t)(rb + 16 + l15) * DIM) + q;
#pragma unroll
    for (int ks = 0; ks < 8; ++ks) {
        afrag0[ks] = arow0[ks * 4];
        afrag1[ks] = arow1[ks * 4];
    }

    int rowcls0[4], rowcls1[4];
#pragma unroll
    for (int j = 0; j < 4; ++j) {
        rowcls0[j] = tlab[rb + q * 4 + j];
        rowcls1[j] = tlab[rb + 16 + q * 4 + j];
    }

    float sump0[4] = {0, 0, 0, 0}, sumn0[4] = {0, 0, 0, 0};
    float sump1[4] = {0, 0, 0, 0}, sumn1[4] = {0, 0, 0, 0};

    const char* bsrc = (const char*)Bt
        + ((size_t)blockIdx.y * NTILES) * 16384 + tid * 16;
    char* ldsd = lds + tid * 16;

    stage_tile(bsrc, ldsd, 0, 0);

    for (int t = 0; t < NTILES; ++t) {
        __syncthreads();   // tile t staged; buffer t+1 free to overwrite
        if (t + 1 < NTILES) stage_tile(bsrc, ldsd, t + 1, (t + 1) & 1);

        const int cc0 = itgt[cb0 + t * 32 + l15];
        const int cc1 = itgt[cb0 + t * 32 + 16 + l15];

        f32x4 acc00 = {0, 0, 0, 0}, acc01 = {0, 0, 0, 0};
        f32x4 acc10 = {0, 0, 0, 0}, acc11 = {0, 0, 0, 0};
        const char* bb = lds + (t & 1) * 16384 + q * 512 + l15 * 16;
#pragma unroll
        for (int ks = 0; ks < 8; ++ks) {
            bf16x8 b0 = *reinterpret_cast<const bf16x8*>(bb + ks * 2048);
            bf16x8 b1 = *reinterpret_cast<const bf16x8*>(bb + ks * 2048 + 256);
            acc00 = __builtin_amdgcn_mfma_f32_16x16x32_bf16(afrag0[ks], b0,
                                                            acc00, 0, 0, 0);
            acc01 = __builtin_amdgcn_mfma_f32_16x16x32_bf16(afrag0[ks], b1,
                                                            acc01, 0, 0, 0);
            acc10 = __builtin_amdgcn_mfma_f32_16x16x32_bf16(afrag1[ks], b0,
                                                            acc10, 0, 0, 0);
            acc11 = __builtin_amdgcn_mfma_f32_16x16x32_bf16(afrag1[ks], b1,
                                                            acc11, 0, 0, 0);
        }

        // Slim epilogue (3 VALU-class instrs/elem uniform; positives rare).
#pragma unroll
        for (int j = 0; j < 4; ++j) {
            epi_one(acc00[j], rowcls0[j] == cc0, sumn0[j], sump0[j]);
            epi_one(acc01[j], rowcls0[j] == cc1, sumn0[j], sump0[j]);
            epi_one(acc10[j], rowcls1[j] == cc0, sumn1[j], sump1[j]);
            epi_one(acc11[j], rowcls1[j] == cc1, sumn1[j], sump1[j]);
        }
    }

    // Reduce over the 16 cols of each quarter-wave, then one atomic per row.
#pragma unroll
    for (int j = 0; j < 4; ++j) {
        float vp0 = sump0[j], vn0 = sumn0[j];
        float vp1 = sump1[j], vn1 = sumn1[j];
#pragma unroll
        for (int m = 1; m < 16; m <<= 1) {
            vp0 += __shfl_xor(vp0, m, 64);
            vn0 += __shfl_xor(vn0, m, 64);
            vp1 += __shfl_xor(vp1, m, 64);
            vn1 += __shfl_xor(vn1, m, 64);
        }
        if (l15 == 0) {
            const int row0 = rb + q * 4 + j;
            atomicAdd(&gsum_p[row0], vp0);
            atomicAdd(&gsum_n[row0], vn0);
            const int row1 = rb + 16 + q * 4 + j;
            atomicAdd(&gsum_p[row1], vp1);
            atomicAdd(&gsum_n[row1], vn1);
        }
    }
}

// lse_{p,n} = (log2(S) + 72) * ln2 ; loss = mean softplus(lse_p + lse_n)
__global__ void finalize_kernel(const float* __restrict__ gsum_p,
                                const float* __restrict__ gsum_n,
                                float* __restrict__ out) {
    __shared__ float red[1024];
    const float LN2 = 0.6931471805599453f;
    const float C2  = 72.0f;
    float acc = 0.f;
    for (int i = threadIdx.x; i < B_ROWS; i += 1024) {
        float zp = (LOG2F(gsum_p[i]) + C2) * LN2;
        float zn = (LOG2F(gsum_n[i]) + C2) * LN2;
        float z  = zp + zn;
        float sp = fmaxf(z, 0.f) + log1pf(expf(-fabsf(z)));
        acc += sp;
    }
    red[threadIdx.x] = acc;
    __syncthreads();
    for (int s = 512; s > 0; s >>= 1) {
        if ((int)threadIdx.x < s) red[threadIdx.x] += red[threadIdx.x + s];
        __syncthreads();
    }
    if (threadIdx.x == 0) out[0] = red[0] / (float)B_ROWS;
}

extern "C" void kernel_launch(void* const* d_in, const int* in_sizes, int n_in,
                              void* d_out, int out_size, void* d_ws, size_t ws_size,
                              hipStream_t stream) {
    const float* text = (const float*)d_in[0];   // [B, D] f32
    const float* img  = (const float*)d_in[1];   // [N, D] f32
    const int* tlab   = (const int*)d_in[2];     // [B]
    const int* itgt   = (const int*)d_in[3];     // [N]
    float* out        = (float*)d_out;           // scalar f32

    char* ws = (char*)d_ws;
    unsigned short* Abf = (unsigned short*)(ws);                            // 4 MB
    unsigned short* Bt  = (unsigned short*)(ws + (size_t)B_ROWS * DIM * 2); // 4 MB
    float* gsum_p = (float*)(ws + (size_t)(B_ROWS + N_COLS) * DIM * 2);
    float* gsum_n = gsum_p + B_ROWS;

    cvt_all_kernel<<<(2 * 262144) / 256, 256, 0, stream>>>(text, img, Abf, Bt,
                                                           gsum_p);

    dim3 grid(B_ROWS / BLK_ROWS, CSPLIT);
    fused_gemm_lse<<<grid, THREADS, 0, stream>>>(Abf, Bt, tlab, itgt,
                                                 gsum_p, gsum_n);

    finalize_kernel<<<1, 1024, 0, stream>>>(gsum_p, gsum_n, out);
}